// Round 1
// baseline (563.826 us; speedup 1.0000x reference)
//
#include <hip/hip_runtime.h>

#define B_   16
#define IC   32
#define OC   64
#define H_   128
#define W_   128
#define KS   3
#define TILE 16
#define SCALE_ 2.0f

// One block = one 16x16 output tile of one batch image.
// Stage (TILE+2)^2 x 32ic input window in LDS, each thread computes all 64
// output channels for its pixel in registers, then min-reduces.
__global__ void conv3_min_kernel(const float* __restrict__ x,
                                 const float* __restrict__ w,
                                 const float* __restrict__ bias,
                                 float* __restrict__ out)
{
    __shared__ float xs[IC][TILE + 2][TILE + 2];   // 32*18*18*4 = 41472 B

    const int b   = blockIdx.z;
    const int ty0 = blockIdx.y * TILE;
    const int tx0 = blockIdx.x * TILE;
    const int tid = threadIdx.x;                   // 0..255

    // ---- stage input tile (with halo, zero-padded at image borders) ----
    const int TOT = IC * (TILE + 2) * (TILE + 2);  // 10368
    for (int idx = tid; idx < TOT; idx += 256) {
        int ic  = idx / ((TILE + 2) * (TILE + 2));
        int rem = idx - ic * ((TILE + 2) * (TILE + 2));
        int r   = rem / (TILE + 2);
        int c   = rem - r * (TILE + 2);
        int gy  = ty0 + r - 1;
        int gx  = tx0 + c - 1;
        float v = 0.0f;
        if ((unsigned)gy < (unsigned)H_ && (unsigned)gx < (unsigned)W_)
            v = x[((b * IC + ic) * H_ + gy) * W_ + gx];
        xs[ic][r][c] = v;
    }
    __syncthreads();

    const int py = tid >> 4;     // 0..15
    const int px = tid & 15;     // 0..15

    float acc[OC];
    #pragma unroll
    for (int oc = 0; oc < OC; ++oc) acc[oc] = 0.0f;

    // ---- main loop: per input channel, 3x3 window in regs, 64 oc FMAs ----
    for (int ic = 0; ic < IC; ++ic) {
        float xv[9];
        #pragma unroll
        for (int dy = 0; dy < 3; ++dy)
            #pragma unroll
            for (int dx = 0; dx < 3; ++dx)
                xv[dy * 3 + dx] = xs[ic][py + dy][px + dx];

        #pragma unroll
        for (int oc = 0; oc < OC; ++oc) {
            const float* wp = w + (oc * IC + ic) * 9;   // wave-uniform address
            #pragma unroll
            for (int k = 0; k < 9; ++k)
                acc[oc] = fmaf(xv[k], wp[k], acc[oc]);
        }
    }

    // ---- epilogue: bias, scale, min over channels ----
    float m = __builtin_inff();
    #pragma unroll
    for (int oc = 0; oc < OC; ++oc)
        m = fminf(m, (acc[oc] + bias[oc]) * SCALE_);

    out[(b * H_ + ty0 + py) * W_ + tx0 + px] = m;
}

extern "C" void kernel_launch(void* const* d_in, const int* in_sizes, int n_in,
                              void* d_out, int out_size, void* d_ws, size_t ws_size,
                              hipStream_t stream)
{
    const float* x    = (const float*)d_in[0];
    const float* w    = (const float*)d_in[1];
    const float* bias = (const float*)d_in[2];
    float* out        = (float*)d_out;

    dim3 grid(W_ / TILE, H_ / TILE, B_);   // (8, 8, 16) = 1024 blocks
    conv3_min_kernel<<<grid, 256, 0, stream>>>(x, w, bias, out);
}

// Round 2
// 93.944 us; speedup vs baseline: 6.0017x; 6.0017x over previous
//
#include <hip/hip_runtime.h>

typedef __attribute__((ext_vector_type(8))) short          bf16x8;   // MFMA A/B frag (8 bf16)
typedef __attribute__((ext_vector_type(8))) unsigned short u16x8;    // staging store
typedef __attribute__((ext_vector_type(4))) float          f32x4;    // MFMA C/D frag

#define Bn 16
#define IC 32
#define OC 64
#define Hh 128
#define Ww 128
#define ROWS 4            // output rows per block
#define INROWS (ROWS + 2) // staged input rows (halo)
#define COLPAD 132        // padded staged width (cols 0..129 used = px -1..128)

__device__ inline unsigned short f2b(float f) {
    // fp32 -> bf16 round-to-nearest-even
    unsigned u = __builtin_bit_cast(unsigned, f);
    unsigned r = (u + 0x7FFFu + ((u >> 16) & 1u)) >> 16;
    return (unsigned short)r;
}

// LDS x layout: [row 0..5][icg 0..3][col 0..131][ic8 0..7] bf16
// => a lane's A-frag (8 consecutive ic for its icg) is one aligned ds_read_b128,
//    16 lanes at consecutive cols are 256B contiguous (conflict-free).
__global__ __launch_bounds__(256, 2)
void conv3_min_mfma(const float* __restrict__ x,
                    const float* __restrict__ w,
                    const float* __restrict__ bias,
                    float* __restrict__ out)
{
    __shared__ __align__(16) unsigned short s[INROWS * 4 * COLPAD * 8]; // 50688 B

    const int tid  = threadIdx.x;
    const int lane = tid & 63;
    const int wid  = tid >> 6;      // wave 0..3
    const int llo  = lane & 15;
    const int lhi  = lane >> 4;
    const int b    = blockIdx.y;
    const int y0   = blockIdx.x * ROWS;

    // ---- phase 1: weights fp32 -> bf16 into LDS, layout [dydx][oc][ic] ----
    for (int idx = tid; idx < 9 * OC * IC; idx += 256) {
        int dydx = idx / (OC * IC);
        int rem  = idx - dydx * OC * IC;
        int oc   = rem >> 5;
        int ic   = rem & 31;
        s[idx] = f2b(w[(oc * IC + ic) * 9 + dydx]);
    }
    __syncthreads();

    // ---- phase 2: all 36 B-fragments -> registers (reused for all rows) ----
    // B frag: n(col)=llo, k = lhi*8 + j (8 contiguous ic)
    bf16x8 bw[9][4];
    #pragma unroll
    for (int dydx = 0; dydx < 9; ++dydx)
        #pragma unroll
        for (int nf = 0; nf < 4; ++nf)
            bw[dydx][nf] = *(const bf16x8*)&s[(dydx * OC + nf * 16 + llo) * IC + lhi * 8];

    float bias_s[4];
    #pragma unroll
    for (int nf = 0; nf < 4; ++nf) bias_s[nf] = bias[nf * 16 + llo];

    __syncthreads();   // before overwriting weight area with x tile

    // ---- phase 3: x tile fp32 -> bf16 into LDS ----
    const float* xb = x + (size_t)b * IC * Hh * Ww;
    for (int it = tid; it < INROWS * 4 * 130; it += 256) {
        int row = it / (4 * 130);
        int rem = it - row * (4 * 130);
        int icg = rem / 130;
        int col = rem - icg * 130;
        int gy  = y0 - 1 + row;     // input row
        int gx  = col - 1;          // input col
        u16x8 pk;
        if ((unsigned)gy < 128u && (unsigned)gx < 128u) {
            const float* xp = xb + (size_t)(icg * 8) * (Hh * Ww) + gy * Ww + gx;
            #pragma unroll
            for (int j = 0; j < 8; ++j) pk[j] = f2b(xp[j * (Hh * Ww)]);
        } else {
            #pragma unroll
            for (int j = 0; j < 8; ++j) pk[j] = 0;
        }
        *(u16x8*)&s[((row * 4 + icg) * COLPAD + col) * 8] = pk;
    }
    __syncthreads();

    // ---- phase 4: 9 shifted K=32 MFMA GEMMs per output row ----
    const int px0 = wid * 32;       // wave's 32-pixel strip
    for (int r = 0; r < ROWS; ++r) {
        f32x4 acc[2][4];
        #pragma unroll
        for (int m = 0; m < 2; ++m)
            #pragma unroll
            for (int nf = 0; nf < 4; ++nf)
                acc[m][nf] = (f32x4){0.f, 0.f, 0.f, 0.f};

        #pragma unroll
        for (int dy = 0; dy < 3; ++dy) {
            #pragma unroll
            for (int dx = 0; dx < 3; ++dx) {
                const int dydx = dy * 3 + dx;
                // A frag: m(row)=llo (pixel), k = lhi*8 + j (ic)
                bf16x8 a0 = *(const bf16x8*)&s[(((r + dy) * 4 + lhi) * COLPAD + (px0 + llo + dx)) * 8];
                bf16x8 a1 = *(const bf16x8*)&s[(((r + dy) * 4 + lhi) * COLPAD + (px0 + 16 + llo + dx)) * 8];
                #pragma unroll
                for (int nf = 0; nf < 4; ++nf) {
                    acc[0][nf] = __builtin_amdgcn_mfma_f32_16x16x32_bf16(a0, bw[dydx][nf], acc[0][nf], 0, 0, 0);
                    acc[1][nf] = __builtin_amdgcn_mfma_f32_16x16x32_bf16(a1, bw[dydx][nf], acc[1][nf], 0, 0, 0);
                }
            }
        }

        // ---- epilogue: bias, min over 64 oc, scale, store ----
        // C layout: col(oc)=llo, row(pixel)= lhi*4 + j
        #pragma unroll
        for (int m = 0; m < 2; ++m) {
            f32x4 vout;
            #pragma unroll
            for (int j = 0; j < 4; ++j) {
                float v = fminf(fminf(acc[m][0][j] + bias_s[0], acc[m][1][j] + bias_s[1]),
                                fminf(acc[m][2][j] + bias_s[2], acc[m][3][j] + bias_s[3]));
                v = fminf(v, __shfl_xor(v, 1, 64));
                v = fminf(v, __shfl_xor(v, 2, 64));
                v = fminf(v, __shfl_xor(v, 4, 64));
                v = fminf(v, __shfl_xor(v, 8, 64));
                vout[j] = v * 2.0f;   // SCALE after min (SCALE > 0, commutes)
            }
            if (llo == 0) {
                float* op = out + ((size_t)b * Hh + (y0 + r)) * Ww + px0 + m * 16 + lhi * 4;
                *(f32x4*)op = vout;
            }
        }
    }
}

extern "C" void kernel_launch(void* const* d_in, const int* in_sizes, int n_in,
                              void* d_out, int out_size, void* d_ws, size_t ws_size,
                              hipStream_t stream)
{
    const float* x    = (const float*)d_in[0];
    const float* w    = (const float*)d_in[1];
    const float* bias = (const float*)d_in[2];
    float* out        = (float*)d_out;

    dim3 grid(Hh / ROWS, Bn);   // (32, 16) = 512 blocks, 256 threads (4 waves)
    conv3_min_mfma<<<grid, 256, 0, stream>>>(x, w, bias, out);
}